// Round 7
// baseline (157.093 us; speedup 1.0000x reference)
//
#include <hip/hip_runtime.h>
#include <math.h>

#define VOCAB 100000
#define NB    1024
#define QLEN  32
#define DLEN  256
#define EMBED 128
#define KNUM  11

typedef __attribute__((ext_vector_type(8))) short bf16x8;   // 8 bf16 = 4 VGPRs
typedef __attribute__((ext_vector_type(4))) float f32x4;

// Gaussian chain: mus -0.9..0.9 step 0.2 (sigma 0.1) + exact mu=1 sigma=.001
#define HALF_L2E 0.7213475204444817f   // 0.5*log2(e)
#define TWO_L2E  2.8853900817779268f   // 2*log2(e)
#define EM4      0.018315638888734179f // e^-4

// Per-wave private sim half-tile: [m=16][n=64], row stride 68 (16B-aligned rows,
// writes 2-way bank aliasing = free, b128 reads ~2-way).
#define SSTR  68
#define SHALF (16 * SSTR)

// ---------- prepass: fp32 table -> bf16 table + bf16-consistent inv-norms ----
__global__ __launch_bounds__(256)
void cvt_table(const float* __restrict__ emb, ushort* __restrict__ ebf,
               float* __restrict__ inorm)
{
    const int row = blockIdx.x * 8 + (threadIdx.x >> 5);
    const int l32 = threadIdx.x & 31;
    const float4 v = *((const float4*)(emb + (size_t)row * EMBED) + l32);
    union { float f; unsigned u; } x0, x1, x2, x3;
    x0.f = v.x; x1.f = v.y; x2.f = v.z; x3.f = v.w;
    const unsigned r0 = x0.u + 0x8000u, r1 = x1.u + 0x8000u;  // round-half-up
    const unsigned r2 = x2.u + 0x8000u, r3 = x3.u + 0x8000u;
    uint2 packed;
    packed.x = (r0 >> 16) | (r1 & 0xFFFF0000u);
    packed.y = (r2 >> 16) | (r3 & 0xFFFF0000u);
    *((uint2*)(ebf + (size_t)row * EMBED) + l32) = packed;
    x0.u = r0 & 0xFFFF0000u; x1.u = r1 & 0xFFFF0000u;
    x2.u = r2 & 0xFFFF0000u; x3.u = r3 & 0xFFFF0000u;
    float n = x0.f * x0.f + x1.f * x1.f + x2.f * x2.f + x3.f * x3.f;
    #pragma unroll
    for (int m = 1; m < 32; m <<= 1) n += __shfl_xor(n, m);
    if (l32 == 0) inorm[row] = __builtin_amdgcn_rsqf(n);
}

// fallback: convert 8 floats -> bf16 frag, accumulate norm of rounded values
__device__ __forceinline__ bf16x8 cvt8(const float* p, float& nacc)
{
    uint4 a = *((const uint4*)p);
    uint4 b = *((const uint4*)(p + 4));
    unsigned u[8] = {a.x, a.y, a.z, a.w, b.x, b.y, b.z, b.w};
    bf16x8 r;
    #pragma unroll
    for (int i = 0; i < 8; ++i) {
        const unsigned q = u[i] + 0x8000u;
        r[i] = (short)(q >> 16);
        union { unsigned uu; float ff; } g; g.uu = q & 0xFFFF0000u;
        nacc = fmaf(g.ff, g.ff, nacc);
    }
    return r;
}

// pool one 16-row half-tile: write sims, exp-chain, reduce, atomic into s_tot
__device__ __forceinline__ void pool_half(float* __restrict__ wtile,
                                          const f32x4* __restrict__ a,   // [4] nt
                                          const float* __restrict__ riq, // [4] r
                                          const float* __restrict__ idn, // [4] nt
                                          float (*__restrict__ stot)[12],
                                          int mtbase, int l15, int quad)
{
    #pragma unroll
    for (int nt = 0; nt < 4; ++nt)
        #pragma unroll
        for (int r = 0; r < 4; ++r)
            wtile[(quad * 4 + r) * SSTR + nt * 16 + l15] = a[nt][r] * riq[r] * idn[nt];

    const float* rp = wtile + l15 * SSTR + quad * 16;   // row l15, chunk quad
    float ksum[KNUM];
    #pragma unroll
    for (int k = 0; k < KNUM; ++k) ksum[k] = 0.f;

    #pragma unroll
    for (int i = 0; i < 4; ++i) {
        const f32x4 sv = *((const f32x4*)(rp + 4 * i));
        #pragma unroll
        for (int e = 0; e < 4; ++e) {
            const float s  = sv[e];
            const float z  = fmaf(s, 10.f, -1.f);
            const float e0 = exp2f(-HALF_L2E * (z * z));
            float ru = exp2f(fmaf(z,  TWO_L2E, -TWO_L2E));
            float rd = exp2f(fmaf(z, -TWO_L2E, -TWO_L2E));
            ksum[5] += e0;
            float tt = e0;
            tt *= ru; ksum[6] += tt; ru *= EM4;
            tt *= ru; ksum[7] += tt; ru *= EM4;
            tt *= ru; ksum[8] += tt; ru *= EM4;
            tt *= ru; ksum[9] += tt;
            tt = e0;
            tt *= rd; ksum[4] += tt; rd *= EM4;
            tt *= rd; ksum[3] += tt; rd *= EM4;
            tt *= rd; ksum[2] += tt; rd *= EM4;
            tt *= rd; ksum[1] += tt; rd *= EM4;
            tt *= rd; ksum[0] += tt;
            // exact kernel (sigma=.001): ==1 iff token match (bf16 self-sim
            // 1+-3e-6; non-match needs cos>0.995 ~ 11 sigma of cos dist)
            ksum[10] += (s > 0.995f) ? 1.f : 0.f;
        }
    }
    #pragma unroll
    for (int k = 0; k < KNUM; ++k) {
        ksum[k] += __shfl_xor(ksum[k], 16);
        ksum[k] += __shfl_xor(ksum[k], 32);
    }
    if (quad == 0) {
        #pragma unroll
        for (int k = 0; k < KNUM; ++k)
            atomicAdd(&stot[mtbase + l15][k], ksum[k]);
    }
}

// One block (4 waves) per batch, BOTH pairs. Wave w owns doc tiles w*4..w*4+3.
// Pair B's 24 fragment loads are issued BEFORE pool A and pinned there by a
// sched_barrier so they stay in flight (in VGPRs) under the exp-chain VALU
// work. launch_bounds(256,2) -> 256-VGPR cap, room for ~96 prefetch regs.
template<bool PRE>
__global__ __launch_bounds__(256, 2)
void knrm_fused(const float* __restrict__ emb,
                const ushort* __restrict__ ebf,
                const float* __restrict__ inorm,
                const float* __restrict__ mlp_w,
                const int* __restrict__ q1, const int* __restrict__ d1,
                const int* __restrict__ q2, const int* __restrict__ d2,
                float* __restrict__ out)
{
    const int b    = blockIdx.x;
    const int t    = threadIdx.x;
    const int w    = t >> 6;
    const int l15  = t & 15;
    const int quad = (t & 63) >> 4;

    const int* __restrict__ qryA = q1 + b * QLEN;
    const int* __restrict__ docA = d1 + b * DLEN;
    const int* __restrict__ qryB = q2 + b * QLEN;
    const int* __restrict__ docB = d2 + b * DLEN;

    __shared__ __align__(16) float s_sim[4 * SHALF];   // 17408 B wave-private
    __shared__ float s_tot[2][QLEN][12];               // 3072 B

    #pragma unroll
    for (int i = t; i < 2 * QLEN * 12; i += 256) ((float*)s_tot)[i] = 0.f;
    __syncthreads();

    const int qidA0 = qryA[l15], qidA1 = qryA[l15 + 16];
    const int qidB0 = qryB[l15], qidB1 = qryB[l15 + 16];
    int didA[4], didB[4];
    #pragma unroll
    for (int nt = 0; nt < 4; ++nt) {
        didA[nt] = docA[(w * 4 + nt) * 16 + l15];
        didB[nt] = docB[(w * 4 + nt) * 16 + l15];
    }

    f32x4 acc[2][4];
    #pragma unroll
    for (int mt = 0; mt < 2; ++mt)
        #pragma unroll
        for (int nt = 0; nt < 4; ++nt)
            acc[mt][nt] = (f32x4){0.f, 0.f, 0.f, 0.f};

    float idnA[4], idnB[4], riqA[2][4], riqB[2][4];
    float* wtile = s_sim + w * SHALF;

    if (PRE) {
        // ---- pair A MFMA (loads inline) ----
        const ushort* qa0 = ebf + (size_t)qidA0 * EMBED + quad * 8;
        const ushort* qa1 = ebf + (size_t)qidA1 * EMBED + quad * 8;
        #pragma unroll
        for (int kk = 0; kk < 4; ++kk) {
            const bf16x8 a0 = *((const bf16x8*)(qa0 + kk * 32));
            const bf16x8 a1 = *((const bf16x8*)(qa1 + kk * 32));
            #pragma unroll
            for (int nt = 0; nt < 4; ++nt) {
                const bf16x8 bb = *((const bf16x8*)(ebf + (size_t)didA[nt] * EMBED + quad * 8 + kk * 32));
                acc[0][nt] = __builtin_amdgcn_mfma_f32_16x16x32_bf16(a0, bb, acc[0][nt], 0, 0, 0);
                acc[1][nt] = __builtin_amdgcn_mfma_f32_16x16x32_bf16(a1, bb, acc[1][nt], 0, 0, 0);
            }
        }

        // ---- prefetch pair B fragments + all norms ----
        bf16x8 pq0[4], pq1[4], pdb[4][4];
        const ushort* qb0 = ebf + (size_t)qidB0 * EMBED + quad * 8;
        const ushort* qb1 = ebf + (size_t)qidB1 * EMBED + quad * 8;
        #pragma unroll
        for (int kk = 0; kk < 4; ++kk) {
            pq0[kk] = *((const bf16x8*)(qb0 + kk * 32));
            pq1[kk] = *((const bf16x8*)(qb1 + kk * 32));
            #pragma unroll
            for (int nt = 0; nt < 4; ++nt)
                pdb[nt][kk] = *((const bf16x8*)(ebf + (size_t)didB[nt] * EMBED + quad * 8 + kk * 32));
        }
        #pragma unroll
        for (int nt = 0; nt < 4; ++nt) { idnA[nt] = inorm[didA[nt]]; idnB[nt] = inorm[didB[nt]]; }
        #pragma unroll
        for (int r = 0; r < 4; ++r) {
            riqA[0][r] = inorm[qryA[quad * 4 + r]];
            riqA[1][r] = inorm[qryA[16 + quad * 4 + r]];
            riqB[0][r] = inorm[qryB[quad * 4 + r]];
            riqB[1][r] = inorm[qryB[16 + quad * 4 + r]];
        }

        // Pin every load above this point: nothing may cross, so all pair-B
        // gathers are in flight while pool A's exp-chain VALU runs.
        __builtin_amdgcn_sched_barrier(0);

        // ---- pool pair A (pair B loads drain underneath) ----
        pool_half(wtile, acc[0], riqA[0], idnA, s_tot[0], 0,  l15, quad);
        pool_half(wtile, acc[1], riqA[1], idnA, s_tot[0], 16, l15, quad);

        // ---- pair B MFMA from prefetched fragments ----
        #pragma unroll
        for (int mt = 0; mt < 2; ++mt)
            #pragma unroll
            for (int nt = 0; nt < 4; ++nt)
                acc[mt][nt] = (f32x4){0.f, 0.f, 0.f, 0.f};
        #pragma unroll
        for (int kk = 0; kk < 4; ++kk)
            #pragma unroll
            for (int nt = 0; nt < 4; ++nt) {
                acc[0][nt] = __builtin_amdgcn_mfma_f32_16x16x32_bf16(pq0[kk], pdb[nt][kk], acc[0][nt], 0, 0, 0);
                acc[1][nt] = __builtin_amdgcn_mfma_f32_16x16x32_bf16(pq1[kk], pdb[nt][kk], acc[1][nt], 0, 0, 0);
            }

        pool_half(wtile, acc[0], riqB[0], idnB, s_tot[1], 0,  l15, quad);
        pool_half(wtile, acc[1], riqB[1], idnB, s_tot[1], 16, l15, quad);
    } else {
        // fallback (no workspace): sequential pairs, inline fp32->bf16
        #pragma unroll
        for (int p = 0; p < 2; ++p) {
            const int* qry = p == 0 ? qryA : qryB;
            const int qi0 = p == 0 ? qidA0 : qidB0;
            const int qi1 = p == 0 ? qidA1 : qidB1;
            const int* did = p == 0 ? didA : didB;
            float qn2[2] = {0.f, 0.f}, dn2[4] = {0.f, 0.f, 0.f, 0.f};
            #pragma unroll
            for (int mt = 0; mt < 2; ++mt)
                #pragma unroll
                for (int nt = 0; nt < 4; ++nt)
                    acc[mt][nt] = (f32x4){0.f, 0.f, 0.f, 0.f};
            const float* qp0 = emb + (size_t)qi0 * EMBED + quad * 8;
            const float* qp1 = emb + (size_t)qi1 * EMBED + quad * 8;
            #pragma unroll
            for (int kk = 0; kk < 4; ++kk) {
                const bf16x8 a0 = cvt8(qp0 + kk * 32, qn2[0]);
                const bf16x8 a1 = cvt8(qp1 + kk * 32, qn2[1]);
                #pragma unroll
                for (int nt = 0; nt < 4; ++nt) {
                    const bf16x8 bb = cvt8(emb + (size_t)did[nt] * EMBED + quad * 8 + kk * 32, dn2[nt]);
                    acc[0][nt] = __builtin_amdgcn_mfma_f32_16x16x32_bf16(a0, bb, acc[0][nt], 0, 0, 0);
                    acc[1][nt] = __builtin_amdgcn_mfma_f32_16x16x32_bf16(a1, bb, acc[1][nt], 0, 0, 0);
                }
            }
            float idn[4], riq[2][4];
            #pragma unroll
            for (int i = 0; i < 2; ++i) {
                qn2[i] += __shfl_xor(qn2[i], 16);
                qn2[i] += __shfl_xor(qn2[i], 32);
            }
            #pragma unroll
            for (int nt = 0; nt < 4; ++nt) {
                dn2[nt] += __shfl_xor(dn2[nt], 16);
                dn2[nt] += __shfl_xor(dn2[nt], 32);
                idn[nt] = __builtin_amdgcn_rsqf(dn2[nt]);
            }
            #pragma unroll
            for (int r = 0; r < 4; ++r) {
                riq[0][r] = __builtin_amdgcn_rsqf(__shfl(qn2[0], quad * 4 + r));
                riq[1][r] = __builtin_amdgcn_rsqf(__shfl(qn2[1], quad * 4 + r));
            }
            pool_half(wtile, acc[0], riq[0], idn, s_tot[p], 0,  l15, quad);
            pool_half(wtile, acc[1], riq[1], idn, s_tot[p], 16, l15, quad);
        }
    }
    __syncthreads();

    // ---- epilogue: logit diff + sigmoid (mlp bias cancels) ----
    if (t < QLEN) {
        float c = 0.f;
        #pragma unroll
        for (int k = 0; k < KNUM; ++k)
            c += mlp_w[k] * (log1pf(s_tot[0][t][k]) - log1pf(s_tot[1][t][k]));
        #pragma unroll
        for (int mm = 1; mm < 32; mm <<= 1) c += __shfl_xor(c, mm);
        if (t == 0) out[b] = 1.f / (1.f + __expf(-c));
    }
}

extern "C" void kernel_launch(void* const* d_in, const int* in_sizes, int n_in,
                              void* d_out, int out_size, void* d_ws, size_t ws_size,
                              hipStream_t stream)
{
    const float* emb   = (const float*)d_in[0];
    const float* mlp_w = (const float*)d_in[1];
    // mlp_b (d_in[2]) unused: cancels in logits1 - logits2
    const int* q1 = (const int*)d_in[3];
    const int* d1 = (const int*)d_in[4];
    const int* q2 = (const int*)d_in[5];
    const int* d2 = (const int*)d_in[6];

    float* out = (float*)d_out;

    const size_t need = (size_t)VOCAB * 4                // inorm
                      + (size_t)VOCAB * EMBED * 2 + 256; // bf16 table
    if (ws_size >= need) {
        float*  inorm = (float*)d_ws;
        ushort* ebf   = (ushort*)(inorm + VOCAB);
        cvt_table<<<VOCAB / 8, 256, 0, stream>>>(emb, ebf, inorm);
        knrm_fused<true><<<NB, 256, 0, stream>>>(emb, ebf, inorm, mlp_w,
                                                 q1, d1, q2, d2, out);
    } else {
        knrm_fused<false><<<NB, 256, 0, stream>>>(emb, nullptr, nullptr, mlp_w,
                                                  q1, d1, q2, d2, out);
    }
}

// Round 8
// 156.435 us; speedup vs baseline: 1.0042x; 1.0042x over previous
//
#include <hip/hip_runtime.h>
#include <math.h>

#define VOCAB 100000
#define NB    1024
#define QLEN  32
#define DLEN  256
#define EMBED 128
#define KNUM  11

typedef __attribute__((ext_vector_type(8))) short bf16x8;   // 8 bf16 = 4 VGPRs
typedef __attribute__((ext_vector_type(4))) float f32x4;

// Gaussian chain: mus -0.9..0.9 step 0.2 (sigma 0.1) + exact mu=1 sigma=.001
#define HALF_L2E 0.7213475204444817f   // 0.5*log2(e)
#define TWO_L2E  2.8853900817779268f   // 2*log2(e)
#define EM4      0.018315638888734179f // e^-4

// sim tile: [m][n] row stride 68 words (16B-aligned rows, 2-way banks = free)
#define SSTR  68
#define SHALF (16 * SSTR)

// async global->LDS, 16 B per lane; LDS dest is WAVE-UNIFORM base, HW scatters
// to base + lane*16 (guide §5 m97/m104). Data never touches VGPRs.
typedef const __attribute__((address_space(1))) unsigned int gu32;
typedef __attribute__((address_space(3))) unsigned int lu32;
__device__ __forceinline__ void load_lds16(const void* g, void* l)
{
    __builtin_amdgcn_global_load_lds((gu32*)g, (lu32*)l, 16, 0, 0);
}

// ---------- prepass: fp32 table -> bf16 table + bf16-consistent inv-norms ----
__global__ __launch_bounds__(256)
void cvt_table(const float* __restrict__ emb, ushort* __restrict__ ebf,
               float* __restrict__ inorm)
{
    const int row = blockIdx.x * 8 + (threadIdx.x >> 5);
    const int l32 = threadIdx.x & 31;
    const float4 v = *((const float4*)(emb + (size_t)row * EMBED) + l32);
    union { float f; unsigned u; } x0, x1, x2, x3;
    x0.f = v.x; x1.f = v.y; x2.f = v.z; x3.f = v.w;
    const unsigned r0 = x0.u + 0x8000u, r1 = x1.u + 0x8000u;  // round-half-up
    const unsigned r2 = x2.u + 0x8000u, r3 = x3.u + 0x8000u;
    uint2 packed;
    packed.x = (r0 >> 16) | (r1 & 0xFFFF0000u);
    packed.y = (r2 >> 16) | (r3 & 0xFFFF0000u);
    *((uint2*)(ebf + (size_t)row * EMBED) + l32) = packed;
    x0.u = r0 & 0xFFFF0000u; x1.u = r1 & 0xFFFF0000u;
    x2.u = r2 & 0xFFFF0000u; x3.u = r3 & 0xFFFF0000u;
    float n = x0.f * x0.f + x1.f * x1.f + x2.f * x2.f + x3.f * x3.f;
    #pragma unroll
    for (int m = 1; m < 32; m <<= 1) n += __shfl_xor(n, m);
    if (l32 == 0) inorm[row] = __builtin_amdgcn_rsqf(n);
}

// fallback helper: fp32 -> bf16 frag + norm of rounded values
__device__ __forceinline__ bf16x8 cvt8(const float* p, float& nacc)
{
    uint4 a = *((const uint4*)p);
    uint4 b = *((const uint4*)(p + 4));
    unsigned u[8] = {a.x, a.y, a.z, a.w, b.x, b.y, b.z, b.w};
    bf16x8 r;
    #pragma unroll
    for (int i = 0; i < 8; ++i) {
        const unsigned q = u[i] + 0x8000u;
        r[i] = (short)(q >> 16);
        union { unsigned uu; float ff; } g; g.uu = q & 0xFFFF0000u;
        nacc = fmaf(g.ff, g.ff, nacc);
    }
    return r;
}

// pool one 16-row half-tile: write sims, exp-chain, reduce, atomic into s_tot
__device__ __forceinline__ void pool_half(float* __restrict__ wtile,
                                          const f32x4* __restrict__ a,   // [4] nt
                                          const float* __restrict__ riq, // [4] r
                                          const float* __restrict__ idn, // [4] nt
                                          float (*__restrict__ stot)[12],
                                          int mtbase, int l15, int quad)
{
    #pragma unroll
    for (int nt = 0; nt < 4; ++nt)
        #pragma unroll
        for (int r = 0; r < 4; ++r)
            wtile[(quad * 4 + r) * SSTR + nt * 16 + l15] = a[nt][r] * riq[r] * idn[nt];

    const float* rp = wtile + l15 * SSTR + quad * 16;   // row l15, chunk quad
    float ksum[KNUM];
    #pragma unroll
    for (int k = 0; k < KNUM; ++k) ksum[k] = 0.f;

    #pragma unroll
    for (int i = 0; i < 4; ++i) {
        const f32x4 sv = *((const f32x4*)(rp + 4 * i));
        #pragma unroll
        for (int e = 0; e < 4; ++e) {
            const float s  = sv[e];
            const float z  = fmaf(s, 10.f, -1.f);
            const float e0 = exp2f(-HALF_L2E * (z * z));
            float ru = exp2f(fmaf(z,  TWO_L2E, -TWO_L2E));
            float rd = exp2f(fmaf(z, -TWO_L2E, -TWO_L2E));
            ksum[5] += e0;
            float tt = e0;
            tt *= ru; ksum[6] += tt; ru *= EM4;
            tt *= ru; ksum[7] += tt; ru *= EM4;
            tt *= ru; ksum[8] += tt; ru *= EM4;
            tt *= ru; ksum[9] += tt;
            tt = e0;
            tt *= rd; ksum[4] += tt; rd *= EM4;
            tt *= rd; ksum[3] += tt; rd *= EM4;
            tt *= rd; ksum[2] += tt; rd *= EM4;
            tt *= rd; ksum[1] += tt; rd *= EM4;
            tt *= rd; ksum[0] += tt;
            // exact kernel (sigma=.001): ==1 iff token match (bf16 self-sim
            // 1+-3e-6; non-match needs cos>0.995 ~ 11 sigma)
            ksum[10] += (s > 0.995f) ? 1.f : 0.f;
        }
    }
    #pragma unroll
    for (int k = 0; k < KNUM; ++k) {
        ksum[k] += __shfl_xor(ksum[k], 16);
        ksum[k] += __shfl_xor(ksum[k], 32);
    }
    if (quad == 0) {
        #pragma unroll
        for (int k = 0; k < KNUM; ++k)
            atomicAdd(&stot[mtbase + l15][k], ksum[k]);
    }
}

// One block (4 waves) per (batch, pair). All row gathers go through
// global_load_lds (zero VGPR pressure -> all DMAs concurrently in flight).
// Query fragments staged once per block (waves share them). Sim tiles
// overlay the consumed doc staging (DS pipe is per-wave in-order).
__global__ __launch_bounds__(256)
void knrm_pair(const ushort* __restrict__ ebf,
               const float* __restrict__ inorm,
               const float* __restrict__ mlp_w,
               const int* __restrict__ q1, const int* __restrict__ d1,
               const int* __restrict__ q2, const int* __restrict__ d2,
               float* __restrict__ logits)
{
    const int b    = blockIdx.x;
    const int pair = blockIdx.y;
    const int t    = threadIdx.x;
    const int w    = t >> 6;
    const int lane = t & 63;
    const int l15  = t & 15;
    const int quad = lane >> 4;

    const int* __restrict__ qry = (pair == 0 ? q1 : q2) + b * QLEN;
    const int* __restrict__ doc = (pair == 0 ? d1 : d2) + b * DLEN;

    // doc staging: [wave][nt][kk] x 1024 B = 64 KB; q staging: [qtile][kk] = 8 KB
    __shared__ __align__(16) char s_stage[4 * 16 * 1024 + 8 * 1024];
    __shared__ float s_tot[QLEN][12];                  // 1536 B
    char* dstage = s_stage;
    char* qstage = s_stage + 4 * 16 * 1024;

    #pragma unroll
    for (int i = t; i < QLEN * 12; i += 256) ((float*)s_tot)[i] = 0.f;

    int did[4];
    #pragma unroll
    for (int nt = 0; nt < 4; ++nt) did[nt] = doc[(w * 4 + nt) * 16 + l15];

    // ---- issue all staging DMAs (fire-and-forget, no data VGPRs) ----
    #pragma unroll
    for (int nt = 0; nt < 4; ++nt)
        #pragma unroll
        for (int kk = 0; kk < 4; ++kk)
            load_lds16(ebf + (size_t)did[nt] * EMBED + quad * 8 + kk * 32,
                       dstage + (w * 16 + nt * 4 + kk) * 1024);

    #pragma unroll
    for (int ii = 0; ii < 2; ++ii) {             // wave w stages q-slots 2w,2w+1
        const int idx = w * 2 + ii;              // idx = qtile*4 + kk
        const int qtile = idx >> 2, kk = idx & 3;
        load_lds16(ebf + (size_t)qry[qtile * 16 + l15] * EMBED + quad * 8 + kk * 32,
                   qstage + idx * 1024);
    }

    // ---- norms (regular VGPR gathers, drain with the same barrier) ----
    float idn[4], riq[2][4];
    #pragma unroll
    for (int nt = 0; nt < 4; ++nt) idn[nt] = inorm[did[nt]];
    #pragma unroll
    for (int r = 0; r < 4; ++r) {
        riq[0][r] = inorm[qry[quad * 4 + r]];
        riq[1][r] = inorm[qry[16 + quad * 4 + r]];
    }

    __syncthreads();   // per-wave vmcnt(0) drain + barrier: all staging visible

    // ---- fragments from LDS -> MFMA ----
    f32x4 acc[2][4];
    #pragma unroll
    for (int mt = 0; mt < 2; ++mt)
        #pragma unroll
        for (int nt = 0; nt < 4; ++nt)
            acc[mt][nt] = (f32x4){0.f, 0.f, 0.f, 0.f};

    #pragma unroll
    for (int kk = 0; kk < 4; ++kk) {
        const bf16x8 a0 = *((const bf16x8*)(qstage + (0 * 4 + kk) * 1024 + lane * 16));
        const bf16x8 a1 = *((const bf16x8*)(qstage + (1 * 4 + kk) * 1024 + lane * 16));
        #pragma unroll
        for (int nt = 0; nt < 4; ++nt) {
            const bf16x8 bb = *((const bf16x8*)(dstage + (w * 16 + nt * 4 + kk) * 1024 + lane * 16));
            acc[0][nt] = __builtin_amdgcn_mfma_f32_16x16x32_bf16(a0, bb, acc[0][nt], 0, 0, 0);
            acc[1][nt] = __builtin_amdgcn_mfma_f32_16x16x32_bf16(a1, bb, acc[1][nt], 0, 0, 0);
        }
    }

    // ---- pooling: sim tile overlays this wave's consumed doc staging ----
    float* wtile = (float*)(dstage + w * 16 * 1024);   // 4352 B used of 16 KB
    pool_half(wtile, acc[0], riq[0], idn, s_tot, 0,  l15, quad);
    pool_half(wtile, acc[1], riq[1], idn, s_tot, 16, l15, quad);
    __syncthreads();

    if (t < QLEN) {
        float c = 0.f;
        #pragma unroll
        for (int k = 0; k < KNUM; ++k) c += mlp_w[k] * log1pf(s_tot[t][k]);
        #pragma unroll
        for (int mm = 1; mm < 32; mm <<= 1) c += __shfl_xor(c, mm);
        if (t == 0) logits[pair * NB + b] = c;   // mlp bias cancels in l1-l2
    }
}

// fallback (no workspace): R6's verified inline-convert path, both pairs
__global__ __launch_bounds__(256, 2)
void knrm_fallback(const float* __restrict__ emb,
                   const float* __restrict__ mlp_w,
                   const int* __restrict__ q1, const int* __restrict__ d1,
                   const int* __restrict__ q2, const int* __restrict__ d2,
                   float* __restrict__ out)
{
    const int b    = blockIdx.x;
    const int t    = threadIdx.x;
    const int w    = t >> 6;
    const int l15  = t & 15;
    const int quad = (t & 63) >> 4;

    __shared__ __align__(16) float s_sim[4 * SHALF];
    __shared__ float s_tot[2][QLEN][12];

    #pragma unroll
    for (int i = t; i < 2 * QLEN * 12; i += 256) ((float*)s_tot)[i] = 0.f;
    __syncthreads();

    float* wtile = s_sim + w * SHALF;
    f32x4 acc[2][4];

    #pragma unroll
    for (int p = 0; p < 2; ++p) {
        const int* qry = (p == 0 ? q1 : q2) + b * QLEN;
        const int* doc = (p == 0 ? d1 : d2) + b * DLEN;
        const int qi0 = qry[l15], qi1 = qry[l15 + 16];
        int did[4];
        #pragma unroll
        for (int nt = 0; nt < 4; ++nt) did[nt] = doc[(w * 4 + nt) * 16 + l15];
        float qn2[2] = {0.f, 0.f}, dn2[4] = {0.f, 0.f, 0.f, 0.f};
        #pragma unroll
        for (int mt = 0; mt < 2; ++mt)
            #pragma unroll
            for (int nt = 0; nt < 4; ++nt)
                acc[mt][nt] = (f32x4){0.f, 0.f, 0.f, 0.f};
        const float* qp0 = emb + (size_t)qi0 * EMBED + quad * 8;
        const float* qp1 = emb + (size_t)qi1 * EMBED + quad * 8;
        #pragma unroll
        for (int kk = 0; kk < 4; ++kk) {
            const bf16x8 a0 = cvt8(qp0 + kk * 32, qn2[0]);
            const bf16x8 a1 = cvt8(qp1 + kk * 32, qn2[1]);
            #pragma unroll
            for (int nt = 0; nt < 4; ++nt) {
                const bf16x8 bb = cvt8(emb + (size_t)did[nt] * EMBED + quad * 8 + kk * 32, dn2[nt]);
                acc[0][nt] = __builtin_amdgcn_mfma_f32_16x16x32_bf16(a0, bb, acc[0][nt], 0, 0, 0);
                acc[1][nt] = __builtin_amdgcn_mfma_f32_16x16x32_bf16(a1, bb, acc[1][nt], 0, 0, 0);
            }
        }
        float idn[4], riq[2][4];
        #pragma unroll
        for (int i = 0; i < 2; ++i) {
            qn2[i] += __shfl_xor(qn2[i], 16);
            qn2[i] += __shfl_xor(qn2[i], 32);
        }
        #pragma unroll
        for (int nt = 0; nt < 4; ++nt) {
            dn2[nt] += __shfl_xor(dn2[nt], 16);
            dn2[nt] += __shfl_xor(dn2[nt], 32);
            idn[nt] = __builtin_amdgcn_rsqf(dn2[nt]);
        }
        #pragma unroll
        for (int r = 0; r < 4; ++r) {
            riq[0][r] = __builtin_amdgcn_rsqf(__shfl(qn2[0], quad * 4 + r));
            riq[1][r] = __builtin_amdgcn_rsqf(__shfl(qn2[1], quad * 4 + r));
        }
        pool_half(wtile, acc[0], riq[0], idn, s_tot[p], 0,  l15, quad);
        pool_half(wtile, acc[1], riq[1], idn, s_tot[p], 16, l15, quad);
    }
    __syncthreads();

    if (t < QLEN) {
        float c = 0.f;
        #pragma unroll
        for (int k = 0; k < KNUM; ++k)
            c += mlp_w[k] * (log1pf(s_tot[0][t][k]) - log1pf(s_tot[1][t][k]));
        #pragma unroll
        for (int mm = 1; mm < 32; mm <<= 1) c += __shfl_xor(c, mm);
        if (t == 0) out[b] = 1.f / (1.f + __expf(-c));
    }
}

__global__ __launch_bounds__(256)
void knrm_combine(const float* __restrict__ logits, float* __restrict__ out)
{
    const int i = blockIdx.x * blockDim.x + threadIdx.x;
    if (i < NB) {
        const float d = logits[i] - logits[NB + i];
        out[i] = 1.f / (1.f + __expf(-d));
    }
}

extern "C" void kernel_launch(void* const* d_in, const int* in_sizes, int n_in,
                              void* d_out, int out_size, void* d_ws, size_t ws_size,
                              hipStream_t stream)
{
    const float* emb   = (const float*)d_in[0];
    const float* mlp_w = (const float*)d_in[1];
    // mlp_b (d_in[2]) unused: cancels in logits1 - logits2
    const int* q1 = (const int*)d_in[3];
    const int* d1 = (const int*)d_in[4];
    const int* q2 = (const int*)d_in[5];
    const int* d2 = (const int*)d_in[6];

    float* out = (float*)d_out;

    const size_t need = 2 * NB * 4                       // logits
                      + (size_t)VOCAB * 4                // inorm
                      + (size_t)VOCAB * EMBED * 2 + 256; // bf16 table
    if (ws_size >= need) {
        float*  logits = (float*)d_ws;
        float*  inorm  = logits + 2 * NB;
        ushort* ebf    = (ushort*)(inorm + VOCAB);
        cvt_table<<<VOCAB / 8, 256, 0, stream>>>(emb, ebf, inorm);
        dim3 grid(NB, 2);
        knrm_pair<<<grid, 256, 0, stream>>>(ebf, inorm, mlp_w,
                                            q1, d1, q2, d2, logits);
        knrm_combine<<<(NB + 255) / 256, 256, 0, stream>>>(logits, out);
    } else {
        knrm_fallback<<<NB, 256, 0, stream>>>(emb, mlp_w, q1, d1, q2, d2, out);
    }
}

// Round 9
// 145.700 us; speedup vs baseline: 1.0782x; 1.0737x over previous
//
#include <hip/hip_runtime.h>
#include <math.h>

#define VOCAB 100000
#define NB    1024
#define QLEN  32
#define DLEN  256
#define EMBED 128
#define KNUM  11

typedef __attribute__((ext_vector_type(8))) short bf16x8;   // 8 bf16 = 4 VGPRs
typedef __attribute__((ext_vector_type(4))) float f32x4;

// Gaussian chain: mus -0.9..0.9 step 0.2 (sigma 0.1) + exact mu=1 sigma=.001
#define HALF_L2E 0.7213475204444817f   // 0.5*log2(e)
#define TWO_L2E  2.8853900817779268f   // 2*log2(e)
#define EM4      0.018315638888734179f // e^-4

// Per-wave private sim half-tile: [m=16][n=64], row stride 68 (16B-aligned rows,
// writes 2-way bank aliasing = free, b128 reads ~2-way).
#define SSTR  68
#define SHALF (16 * SSTR)

// ---------- prepass: fp32 table -> bf16 table + bf16-consistent inv-norms ----
__global__ __launch_bounds__(256)
void cvt_table(const float* __restrict__ emb, ushort* __restrict__ ebf,
               float* __restrict__ inorm)
{
    const int row = blockIdx.x * 8 + (threadIdx.x >> 5);
    const int l32 = threadIdx.x & 31;
    const float4 v = *((const float4*)(emb + (size_t)row * EMBED) + l32);
    union { float f; unsigned u; } x0, x1, x2, x3;
    x0.f = v.x; x1.f = v.y; x2.f = v.z; x3.f = v.w;
    const unsigned r0 = x0.u + 0x8000u, r1 = x1.u + 0x8000u;  // round-half-up
    const unsigned r2 = x2.u + 0x8000u, r3 = x3.u + 0x8000u;
    uint2 packed;
    packed.x = (r0 >> 16) | (r1 & 0xFFFF0000u);
    packed.y = (r2 >> 16) | (r3 & 0xFFFF0000u);
    *((uint2*)(ebf + (size_t)row * EMBED) + l32) = packed;
    x0.u = r0 & 0xFFFF0000u; x1.u = r1 & 0xFFFF0000u;
    x2.u = r2 & 0xFFFF0000u; x3.u = r3 & 0xFFFF0000u;
    float n = x0.f * x0.f + x1.f * x1.f + x2.f * x2.f + x3.f * x3.f;
    #pragma unroll
    for (int m = 1; m < 32; m <<= 1) n += __shfl_xor(n, m);
    if (l32 == 0) inorm[row] = __builtin_amdgcn_rsqf(n);
}

// fallback helper: fp32 -> bf16 frag + norm of rounded values
__device__ __forceinline__ bf16x8 cvt8(const float* p, float& nacc)
{
    uint4 a = *((const uint4*)p);
    uint4 b = *((const uint4*)(p + 4));
    unsigned u[8] = {a.x, a.y, a.z, a.w, b.x, b.y, b.z, b.w};
    bf16x8 r;
    #pragma unroll
    for (int i = 0; i < 8; ++i) {
        const unsigned q = u[i] + 0x8000u;
        r[i] = (short)(q >> 16);
        union { unsigned uu; float ff; } g; g.uu = q & 0xFFFF0000u;
        nacc = fmaf(g.ff, g.ff, nacc);
    }
    return r;
}

// pool one 16-row half-tile: write sims, exp-chain, reduce, atomic into s_tot
__device__ __forceinline__ void pool_half(float* __restrict__ wtile,
                                          const f32x4* __restrict__ a,   // [4] nt
                                          const float* __restrict__ riq, // [4] r
                                          const float* __restrict__ idn, // [4] nt
                                          float (*__restrict__ stot)[12],
                                          int mtbase, int l15, int quad)
{
    #pragma unroll
    for (int nt = 0; nt < 4; ++nt)
        #pragma unroll
        for (int r = 0; r < 4; ++r)
            wtile[(quad * 4 + r) * SSTR + nt * 16 + l15] = a[nt][r] * riq[r] * idn[nt];

    const float* rp = wtile + l15 * SSTR + quad * 16;   // row l15, chunk quad
    float ksum[KNUM];
    #pragma unroll
    for (int k = 0; k < KNUM; ++k) ksum[k] = 0.f;

    #pragma unroll
    for (int i = 0; i < 4; ++i) {
        const f32x4 sv = *((const f32x4*)(rp + 4 * i));
        #pragma unroll
        for (int e = 0; e < 4; ++e) {
            const float s  = sv[e];
            const float z  = fmaf(s, 10.f, -1.f);
            const float e0 = exp2f(-HALF_L2E * (z * z));
            float ru = exp2f(fmaf(z,  TWO_L2E, -TWO_L2E));
            float rd = exp2f(fmaf(z, -TWO_L2E, -TWO_L2E));
            ksum[5] += e0;
            float tt = e0;
            tt *= ru; ksum[6] += tt; ru *= EM4;
            tt *= ru; ksum[7] += tt; ru *= EM4;
            tt *= ru; ksum[8] += tt; ru *= EM4;
            tt *= ru; ksum[9] += tt;
            tt = e0;
            tt *= rd; ksum[4] += tt; rd *= EM4;
            tt *= rd; ksum[3] += tt; rd *= EM4;
            tt *= rd; ksum[2] += tt; rd *= EM4;
            tt *= rd; ksum[1] += tt; rd *= EM4;
            tt *= rd; ksum[0] += tt;
            // exact kernel (sigma=.001): ==1 iff token match (bf16 self-sim
            // 1+-3e-6; non-match needs cos>0.995 ~ 11 sigma)
            ksum[10] += (s > 0.995f) ? 1.f : 0.f;
        }
    }
    #pragma unroll
    for (int k = 0; k < KNUM; ++k) {
        ksum[k] += __shfl_xor(ksum[k], 16);
        ksum[k] += __shfl_xor(ksum[k], 32);
    }
    if (quad == 0) {
        #pragma unroll
        for (int k = 0; k < KNUM; ++k)
            atomicAdd(&stot[mtbase + l15][k], ksum[k]);
    }
}

// One block (4 waves) per (batch, pair). Wave w owns doc tiles w*4..w*4+3.
// Inline loads (compiler software-pipelines), wave-private sim tiles
// (18.9 KB LDS -> 8 blocks/CU by LDS), launch_bounds(256,4) -> VGPR<=128
// (natural ~90, NO spill). Goal: many resident waves = many outstanding
// gather requests = higher service rate on the random-row path.
template<bool PRE>
__global__ __launch_bounds__(256, 4)
void knrm_pair(const float* __restrict__ emb,
               const ushort* __restrict__ ebf,
               const float* __restrict__ inorm,
               const float* __restrict__ mlp_w,
               const int* __restrict__ q1, const int* __restrict__ d1,
               const int* __restrict__ q2, const int* __restrict__ d2,
               float* __restrict__ logits)
{
    const int b    = blockIdx.x;
    const int pair = blockIdx.y;
    const int t    = threadIdx.x;
    const int w    = t >> 6;
    const int l15  = t & 15;
    const int quad = (t & 63) >> 4;

    const int* __restrict__ qry = (pair == 0 ? q1 : q2) + b * QLEN;
    const int* __restrict__ doc = (pair == 0 ? d1 : d2) + b * DLEN;

    __shared__ __align__(16) float s_sim[4 * SHALF];   // 17408 B wave-private
    __shared__ float s_tot[QLEN][12];                  // 1536 B

    #pragma unroll
    for (int i = t; i < QLEN * 12; i += 256) ((float*)s_tot)[i] = 0.f;
    __syncthreads();

    const int qid0 = qry[l15], qid1 = qry[l15 + 16];
    int did[4];
    #pragma unroll
    for (int nt = 0; nt < 4; ++nt) did[nt] = doc[(w * 4 + nt) * 16 + l15];

    f32x4 acc[2][4];
    #pragma unroll
    for (int mt = 0; mt < 2; ++mt)
        #pragma unroll
        for (int nt = 0; nt < 4; ++nt)
            acc[mt][nt] = (f32x4){0.f, 0.f, 0.f, 0.f};

    float idn[4], riq[2][4];
    float* wtile = s_sim + w * SHALF;

    if (PRE) {
        const ushort* qp0 = ebf + (size_t)qid0 * EMBED + quad * 8;
        const ushort* qp1 = ebf + (size_t)qid1 * EMBED + quad * 8;
        #pragma unroll
        for (int kk = 0; kk < 4; ++kk) {
            const bf16x8 a0 = *((const bf16x8*)(qp0 + kk * 32));
            const bf16x8 a1 = *((const bf16x8*)(qp1 + kk * 32));
            #pragma unroll
            for (int nt = 0; nt < 4; ++nt) {
                const bf16x8 bb = *((const bf16x8*)(ebf + (size_t)did[nt] * EMBED + quad * 8 + kk * 32));
                acc[0][nt] = __builtin_amdgcn_mfma_f32_16x16x32_bf16(a0, bb, acc[0][nt], 0, 0, 0);
                acc[1][nt] = __builtin_amdgcn_mfma_f32_16x16x32_bf16(a1, bb, acc[1][nt], 0, 0, 0);
            }
        }
        #pragma unroll
        for (int nt = 0; nt < 4; ++nt) idn[nt] = inorm[did[nt]];
        #pragma unroll
        for (int r = 0; r < 4; ++r) {
            riq[0][r] = inorm[qry[quad * 4 + r]];
            riq[1][r] = inorm[qry[16 + quad * 4 + r]];
        }
    } else {
        float qn2[2] = {0.f, 0.f}, dn2[4] = {0.f, 0.f, 0.f, 0.f};
        const float* qp0 = emb + (size_t)qid0 * EMBED + quad * 8;
        const float* qp1 = emb + (size_t)qid1 * EMBED + quad * 8;
        #pragma unroll
        for (int kk = 0; kk < 4; ++kk) {
            const bf16x8 a0 = cvt8(qp0 + kk * 32, qn2[0]);
            const bf16x8 a1 = cvt8(qp1 + kk * 32, qn2[1]);
            #pragma unroll
            for (int nt = 0; nt < 4; ++nt) {
                const bf16x8 bb = cvt8(emb + (size_t)did[nt] * EMBED + quad * 8 + kk * 32, dn2[nt]);
                acc[0][nt] = __builtin_amdgcn_mfma_f32_16x16x32_bf16(a0, bb, acc[0][nt], 0, 0, 0);
                acc[1][nt] = __builtin_amdgcn_mfma_f32_16x16x32_bf16(a1, bb, acc[1][nt], 0, 0, 0);
            }
        }
        #pragma unroll
        for (int i = 0; i < 2; ++i) {
            qn2[i] += __shfl_xor(qn2[i], 16);
            qn2[i] += __shfl_xor(qn2[i], 32);
        }
        #pragma unroll
        for (int nt = 0; nt < 4; ++nt) {
            dn2[nt] += __shfl_xor(dn2[nt], 16);
            dn2[nt] += __shfl_xor(dn2[nt], 32);
            idn[nt] = __builtin_amdgcn_rsqf(dn2[nt]);
        }
        #pragma unroll
        for (int r = 0; r < 4; ++r) {
            riq[0][r] = __builtin_amdgcn_rsqf(__shfl(qn2[0], quad * 4 + r));
            riq[1][r] = __builtin_amdgcn_rsqf(__shfl(qn2[1], quad * 4 + r));
        }
    }

    // ---- pooling: wave-private tiles, no barriers ----
    pool_half(wtile, acc[0], riq[0], idn, s_tot, 0,  l15, quad);
    pool_half(wtile, acc[1], riq[1], idn, s_tot, 16, l15, quad);
    __syncthreads();

    if (t < QLEN) {
        float c = 0.f;
        #pragma unroll
        for (int k = 0; k < KNUM; ++k) c += mlp_w[k] * log1pf(s_tot[t][k]);
        #pragma unroll
        for (int mm = 1; mm < 32; mm <<= 1) c += __shfl_xor(c, mm);
        if (t == 0) logits[pair * NB + b] = c;   // mlp bias cancels in l1-l2
    }
}

__global__ __launch_bounds__(256)
void knrm_combine(const float* __restrict__ logits, float* __restrict__ out)
{
    const int i = blockIdx.x * blockDim.x + threadIdx.x;
    if (i < NB) {
        const float d = logits[i] - logits[NB + i];
        out[i] = 1.f / (1.f + __expf(-d));
    }
}

extern "C" void kernel_launch(void* const* d_in, const int* in_sizes, int n_in,
                              void* d_out, int out_size, void* d_ws, size_t ws_size,
                              hipStream_t stream)
{
    const float* emb   = (const float*)d_in[0];
    const float* mlp_w = (const float*)d_in[1];
    // mlp_b (d_in[2]) unused: cancels in logits1 - logits2
    const int* q1 = (const int*)d_in[3];
    const int* d1 = (const int*)d_in[4];
    const int* q2 = (const int*)d_in[5];
    const int* d2 = (const int*)d_in[6];

    float* out = (float*)d_out;

    const size_t need = 2 * NB * 4                       // logits
                      + (size_t)VOCAB * 4                // inorm
                      + (size_t)VOCAB * EMBED * 2 + 256; // bf16 table
    dim3 grid(NB, 2);
    if (ws_size >= need) {
        float*  logits = (float*)d_ws;
        float*  inorm  = logits + 2 * NB;
        ushort* ebf    = (ushort*)(inorm + VOCAB);
        cvt_table<<<VOCAB / 8, 256, 0, stream>>>(emb, ebf, inorm);
        knrm_pair<true><<<grid, 256, 0, stream>>>(emb, ebf, inorm, mlp_w,
                                                  q1, d1, q2, d2, logits);
    } else {
        float* logits = (float*)d_ws;   // fallback still needs 8 KB for logits
        knrm_pair<false><<<grid, 256, 0, stream>>>(emb, nullptr, nullptr, mlp_w,
                                                   q1, d1, q2, d2, logits);
    }
    knrm_combine<<<(NB + 255) / 256, 256, 0, stream>>>((float*)d_ws, out);
}